// Round 3
// baseline (4641.805 us; speedup 1.0000x reference)
//
#include <hip/hip_runtime.h>
#include <math.h>

#define N 4096
#define DIM 64
#define MAX_ITER 50
#define EPS 0.1f
#define INV_EPS 10.0f
#define THRESH 0.1f
#define NBLK 256
#define NTHR 1024

// ws layout (floats): [0,N) u | [N,2N) v | [2N,2N+64) err[MAX_ITER] |
// [2N+64] cost | [2N+65] done_cnt | [2N+66] bar_cnt | [2N+67] bar_gen
__global__ void init_ws(float* __restrict__ ws) {
    int i = blockIdx.x * 256 + threadIdx.x;
    if (i < 2 * N + 128) ws[i] = 0.0f;
}

// ---------------- build D[i][j] = sum_d (A[i][d]-B[j][d])^2 ----------------
__global__ __launch_bounds__(256) void build_dist(const float* __restrict__ A,
                                                  const float* __restrict__ B,
                                                  float* __restrict__ Dst) {
    __shared__ float As[64][68];
    __shared__ float Bs[64][68];
    const int i0 = blockIdx.y << 6, j0 = blockIdx.x << 6;
    const int t = threadIdx.x;
    const float* Ag = A + (size_t)i0 * DIM;
    const float* Bg = B + (size_t)j0 * DIM;
    for (int k = t; k < 4096; k += 256) {
        As[k >> 6][k & 63] = Ag[k];
        Bs[k >> 6][k & 63] = Bg[k];
    }
    __syncthreads();
    const int ty = t >> 4, tx = t & 15;
    float acc[4][4] = {{0.f}};
    for (int d = 0; d < DIM; d += 4) {
        float4 av[4], bv[4];
#pragma unroll
        for (int a = 0; a < 4; ++a) av[a] = *(const float4*)&As[ty + 16 * a][d];
#pragma unroll
        for (int b = 0; b < 4; ++b) bv[b] = *(const float4*)&Bs[tx + 16 * b][d];
#pragma unroll
        for (int a = 0; a < 4; ++a)
#pragma unroll
            for (int b = 0; b < 4; ++b) {
                float d0 = av[a].x - bv[b].x;
                float d1 = av[a].y - bv[b].y;
                float d2 = av[a].z - bv[b].z;
                float d3 = av[a].w - bv[b].w;
                acc[a][b] = fmaf(d0, d0, acc[a][b]);
                acc[a][b] = fmaf(d1, d1, acc[a][b]);
                acc[a][b] = fmaf(d2, d2, acc[a][b]);
                acc[a][b] = fmaf(d3, d3, acc[a][b]);
            }
    }
#pragma unroll
    for (int a = 0; a < 4; ++a) {
        int i = i0 + ty + 16 * a;
        float* drow = Dst + (size_t)i * N + j0;
#pragma unroll
        for (int b = 0; b < 4; ++b) drow[tx + 16 * b] = acc[a][b];
    }
}

// ---------------- grid-wide sense-reversal barrier (cross-XCD safe) --------
__device__ __forceinline__ void grid_barrier(unsigned* cnt, unsigned* gen) {
    __syncthreads();
    if (threadIdx.x == 0) {
        __threadfence();  // release: push u/v/err writes to device scope
        unsigned g = __hip_atomic_load(gen, __ATOMIC_RELAXED, __HIP_MEMORY_SCOPE_AGENT);
        unsigned arrived =
            __hip_atomic_fetch_add(cnt, 1u, __ATOMIC_ACQ_REL, __HIP_MEMORY_SCOPE_AGENT);
        if (arrived == NBLK - 1u) {
            __hip_atomic_store(cnt, 0u, __ATOMIC_RELAXED, __HIP_MEMORY_SCOPE_AGENT);
            __hip_atomic_store(gen, g + 1u, __ATOMIC_RELEASE, __HIP_MEMORY_SCOPE_AGENT);
        } else {
            while (__hip_atomic_load(gen, __ATOMIC_ACQUIRE, __HIP_MEMORY_SCOPE_AGENT) == g)
                __builtin_amdgcn_s_sleep(1);
        }
        __threadfence();  // acquire: invalidate CU L1 before re-reading u/v
    }
    __syncthreads();
}

// ---------------- one row's LSE: target - max_j d - EPS*log(sum exp) -------
// d_j = svec[j] - row[j]; online softmax, single pass over the row.
__device__ __forceinline__ float row_lse_neg(const float4* __restrict__ rowp,
                                             const float* __restrict__ svec,
                                             int lane, float target) {
    float m = -1e30f, s = 0.0f;
#pragma unroll 2
    for (int cb = 0; cb < 8; ++cb) {
        int i0 = (cb * 2 + 0) * 64 + lane;
        int i1 = (cb * 2 + 1) * 64 + lane;
        float4 c0 = rowp[i0];
        float4 c1 = rowp[i1];
        float4 w0 = ((const float4*)svec)[i0];
        float4 w1 = ((const float4*)svec)[i1];
        float d0 = w0.x - c0.x, d1 = w0.y - c0.y, d2 = w0.z - c0.z, d3 = w0.w - c0.w;
        float d4 = w1.x - c1.x, d5 = w1.y - c1.y, d6 = w1.z - c1.z, d7 = w1.w - c1.w;
        float cm = fmaxf(fmaxf(fmaxf(d0, d1), fmaxf(d2, d3)),
                         fmaxf(fmaxf(d4, d5), fmaxf(d6, d7)));
        float mn = fmaxf(m, cm);
        float acc = __expf((d0 - mn) * INV_EPS) + __expf((d1 - mn) * INV_EPS) +
                    __expf((d2 - mn) * INV_EPS) + __expf((d3 - mn) * INV_EPS) +
                    __expf((d4 - mn) * INV_EPS) + __expf((d5 - mn) * INV_EPS) +
                    __expf((d6 - mn) * INV_EPS) + __expf((d7 - mn) * INV_EPS);
        s = s * __expf((m - mn) * INV_EPS) + acc;
        m = mn;
    }
#pragma unroll
    for (int off = 32; off; off >>= 1) {
        float mo = __shfl_xor(m, off);
        float so = __shfl_xor(s, off);
        float mn = fmaxf(m, mo);
        s = s * __expf((m - mn) * INV_EPS) + so * __expf((mo - mn) * INV_EPS);
        m = mn;
    }
    return target - m - EPS * __logf(s);
}

// ---------------- the whole Sinkhorn loop in one persistent kernel ---------
// 256 blocks x 1024 threads; block b owns rows 16b..16b+15 of C and Ct.
// VGPR capped at 64 (launch_bounds min 8 waves/EU) so even a 2-blocks-on-one-CU
// dispatch stays co-resident -> grid barrier cannot deadlock.
__global__ __launch_bounds__(NTHR, 8) void sinkhorn_persist(
    const float* __restrict__ C, const float* __restrict__ Ct,
    float* __restrict__ ws, float* __restrict__ pi, float* __restrict__ out,
    float target) {
    float* u = ws;
    float* v = ws + N;
    float* err = ws + 2 * N;
    float* cost_ws = ws + 2 * N + 64;
    unsigned* done_cnt = (unsigned*)(ws + 2 * N + 65);
    unsigned* bar_cnt = (unsigned*)(ws + 2 * N + 66);
    unsigned* bar_gen = (unsigned*)(ws + 2 * N + 67);

    const int t = threadIdx.x, wave = t >> 6, lane = t & 63;
    const int row = (int)(blockIdx.x << 4) + wave;

    __shared__ float svec[N];  // staged u or v (16 KB)
    __shared__ float red[16];
    __shared__ float bcast;

    const float4* __restrict__ Crow = (const float4*)(C + (size_t)row * N);
    const float4* __restrict__ Ctrow = (const float4*)(Ct + (size_t)row * N);

    float u_loc = 0.0f;

    for (int it = 0; it < MAX_ITER; ++it) {
        // ---- u-update: needs all of v ----
        ((float4*)svec)[t] = ((const float4*)v)[t];
        __syncthreads();
        float un = row_lse_neg(Crow, svec, lane, target);
        if (lane == 0) {
            red[wave] = fabsf(un - u_loc);
            u[row] = un;
        }
        u_loc = un;
        __syncthreads();
        if (t == 0) {
            float e = 0.f;
#pragma unroll
            for (int k = 0; k < 16; ++k) e += red[k];
            atomicAdd(&err[it], e);
        }
        grid_barrier(bar_cnt, bar_gen);

        // ---- v-update: needs all of (new) u ----
        ((float4*)svec)[t] = ((const float4*)u)[t];
        __syncthreads();
        float vn = row_lse_neg(Ctrow, svec, lane, target);
        if (lane == 0) v[row] = vn;
        grid_barrier(bar_cnt, bar_gen);

        // ---- convergence (uniform across grid) == reference's freeze ----
        if (t == 0)
            bcast = __hip_atomic_load(&err[it], __ATOMIC_RELAXED, __HIP_MEMORY_SCOPE_AGENT);
        __syncthreads();
        if (bcast < THRESH) break;
    }

    // ---- final: pi = exp((u_i + v_j - C)/eps), cost = sum(pi*C) ----
    ((float4*)svec)[t] = ((const float4*)v)[t];
    __syncthreads();
    float4* __restrict__ pirow = (float4*)(pi + (size_t)row * N);
    const float ui = u_loc;
    float csum = 0.f;
#pragma unroll 2
    for (int cb = 0; cb < 16; ++cb) {
        int idx = cb * 64 + lane;
        float4 c = Crow[idx];
        float4 w = ((const float4*)svec)[idx];
        float4 p;
        p.x = __expf((ui + w.x - c.x) * INV_EPS);
        p.y = __expf((ui + w.y - c.y) * INV_EPS);
        p.z = __expf((ui + w.z - c.z) * INV_EPS);
        p.w = __expf((ui + w.w - c.w) * INV_EPS);
        pirow[idx] = p;
        csum = fmaf(p.x, c.x, csum);
        csum = fmaf(p.y, c.y, csum);
        csum = fmaf(p.z, c.z, csum);
        csum = fmaf(p.w, c.w, csum);
    }
#pragma unroll
    for (int off = 32; off; off >>= 1) csum += __shfl_xor(csum, off);
    if (lane == 0) red[wave] = csum;
    __syncthreads();
    if (t == 0) {
        float cs = 0.f;
#pragma unroll
        for (int k = 0; k < 16; ++k) cs += red[k];
        atomicAdd(cost_ws, cs);
        __threadfence();
        unsigned a =
            __hip_atomic_fetch_add(done_cnt, 1u, __ATOMIC_ACQ_REL, __HIP_MEMORY_SCOPE_AGENT);
        if (a == NBLK - 1u)
            out[0] = __hip_atomic_load(cost_ws, __ATOMIC_RELAXED, __HIP_MEMORY_SCOPE_AGENT);
    }
}

extern "C" void kernel_launch(void* const* d_in, const int* in_sizes, int n_in,
                              void* d_out, int out_size, void* d_ws, size_t ws_size,
                              hipStream_t stream) {
    const float* x = (const float*)d_in[0];  // [4096,64]
    const float* y = (const float*)d_in[1];  // [4096,64]
    float* out = (float*)d_out;              // [0]=cost, [1..N*N]=pi, [1+N*N..]=C
    float* pi = out + 1;
    float* C = out + 1 + (size_t)N * N;
    float* Ct = out;  // scratch: aliases cost+pi region, dead before final phase
    float* ws = (float*)d_ws;

    init_ws<<<dim3((2 * N + 128 + 255) / 256), dim3(256), 0, stream>>>(ws);

    dim3 bgrid(64, 64);
    build_dist<<<bgrid, dim3(256), 0, stream>>>(x, y, C);   // C[i][j]
    build_dist<<<bgrid, dim3(256), 0, stream>>>(y, x, Ct);  // C^T[j][i]

    float target = EPS * logf(1.0f / (float)N + 1e-8f);  // log_mu == log_nu

    sinkhorn_persist<<<dim3(NBLK), dim3(NTHR), 0, stream>>>(C, Ct, ws, pi, out, target);
}